// Round 2
// baseline (280.833 us; speedup 1.0000x reference)
//
#include <hip/hip_runtime.h>

#define NN   512
#define NIN  256
#define NOUT 256
#define ROWS_PER_BLOCK 2

// Kernel 1: A[i][o] = dot(x[i,:], W[o, 0:256]);  B[i][o] = dot(x[i,:], W[o, 256:512])
// thread t == output channel o; each block handles ROWS_PER_BLOCK rows of x.
__global__ void __launch_bounds__(256) compute_ab_kernel(
    const float* __restrict__ x, const float* __restrict__ W,
    float* __restrict__ A, float* __restrict__ B)
{
    __shared__ __align__(16) float xs[ROWS_PER_BLOCK][NIN];
    const int t  = threadIdx.x;                 // o in [0,256)
    const int i0 = blockIdx.x * ROWS_PER_BLOCK;

    // stage x rows into LDS (coalesced: lane t reads element t of each row)
    for (int r = 0; r < ROWS_PER_BLOCK; ++r)
        xs[r][t] = x[(i0 + r) * NIN + t];
    __syncthreads();

    float acc_a[ROWS_PER_BLOCK];
    float acc_b[ROWS_PER_BLOCK];
    #pragma unroll
    for (int r = 0; r < ROWS_PER_BLOCK; ++r) { acc_a[r] = 0.f; acc_b[r] = 0.f; }

    // W row o = 512 floats = 128 float4: first 64 -> A-half, last 64 -> B-half
    const float4* Wrow = reinterpret_cast<const float4*>(W + (size_t)t * (2 * NIN));

    #pragma unroll 4
    for (int k4 = 0; k4 < NIN / 4; ++k4) {
        const float4 wa = Wrow[k4];
        const float4 wb = Wrow[NIN / 4 + k4];
        #pragma unroll
        for (int r = 0; r < ROWS_PER_BLOCK; ++r) {
            // all lanes read same LDS address -> broadcast, no bank conflict
            const float4 xv = *reinterpret_cast<const float4*>(&xs[r][k4 * 4]);
            acc_a[r] = fmaf(wa.x, xv.x, acc_a[r]);
            acc_a[r] = fmaf(wa.y, xv.y, acc_a[r]);
            acc_a[r] = fmaf(wa.z, xv.z, acc_a[r]);
            acc_a[r] = fmaf(wa.w, xv.w, acc_a[r]);
            acc_b[r] = fmaf(wb.x, xv.x, acc_b[r]);
            acc_b[r] = fmaf(wb.y, xv.y, acc_b[r]);
            acc_b[r] = fmaf(wb.z, xv.z, acc_b[r]);
            acc_b[r] = fmaf(wb.w, xv.w, acc_b[r]);
        }
    }

    for (int r = 0; r < ROWS_PER_BLOCK; ++r) {
        A[(i0 + r) * NOUT + t] = acc_a[r];
        B[(i0 + r) * NOUT + t] = acc_b[r];
    }
}

// Kernel 2: out[i][j][o] = (i==j) ? 0 : A[min][o] + B[max][o] + b[o]
// One float4 per thread-iteration; a wave's 64 lanes cover exactly one (i,j)
// row (branch + min/max are wave-uniform, stores coalesced).
// grid-stride (2048*256 float4) is a multiple of 64 -> o4 is loop-invariant,
// so the bias load is hoisted out of the loop.
__global__ void __launch_bounds__(256) write_out_kernel(
    const float4* __restrict__ A4, const float4* __restrict__ B4,
    const float4* __restrict__ b4, float4* __restrict__ out4)
{
    const int total  = NN * NN * (NOUT / 4);    // 16,777,216 float4
    const int stride = gridDim.x * blockDim.x;  // 524288 (multiple of 64)
    const int e0     = blockIdx.x * blockDim.x + threadIdx.x;
    const int o4     = e0 & (NOUT / 4 - 1);     // invariant across iterations
    const float4 bv  = b4[o4];

    for (int e = e0; e < total; e += stride) {
        const int j = (e >> 6) & (NN - 1);      // (e / 64) % 512
        const int i = e >> 15;                  // e / (64*512)
        float4 v;
        if (i == j) {
            v = make_float4(0.f, 0.f, 0.f, 0.f);
        } else {
            const int p = i < j ? i : j;
            const int q = i < j ? j : i;
            const float4 a  = A4[p * (NOUT / 4) + o4];
            const float4 bb = B4[q * (NOUT / 4) + o4];
            v = make_float4(a.x + bb.x + bv.x,
                            a.y + bb.y + bv.y,
                            a.z + bb.z + bv.z,
                            a.w + bb.w + bv.w);
        }
        out4[e] = v;
    }
}

extern "C" void kernel_launch(void* const* d_in, const int* in_sizes, int n_in,
                              void* d_out, int out_size, void* d_ws, size_t ws_size,
                              hipStream_t stream) {
    const float* x = (const float*)d_in[0];   // [512, 256]
    const float* W = (const float*)d_in[1];   // [256, 512]
    const float* b = (const float*)d_in[2];   // [256]

    float* A = (float*)d_ws;                  // [512, 256] f32
    float* B = A + NN * NOUT;                 // [512, 256] f32  (total 1 MB of ws)

    compute_ab_kernel<<<NN / ROWS_PER_BLOCK, 256, 0, stream>>>(x, W, A, B);
    write_out_kernel<<<2048, 256, 0, stream>>>(
        (const float4*)A, (const float4*)B, (const float4*)b, (float4*)d_out);
}